// Round 3
// baseline (186.291 us; speedup 1.0000x reference)
//
#include <hip/hip_runtime.h>
#include <hip/hip_bf16.h>
#include <stdint.h>

typedef unsigned short u16;
typedef __attribute__((ext_vector_type(8))) __bf16 bf16x8;
typedef __attribute__((ext_vector_type(4))) float f32x4;
typedef __attribute__((ext_vector_type(4))) u16 u16x4;
typedef __attribute__((ext_vector_type(4))) float f32x4v;

typedef __attribute__((address_space(1))) void gvoid_t;
typedef __attribute__((address_space(3))) void lvoid_t;

#define BAR()    asm volatile("s_barrier" ::: "memory")
#define WAITV8() asm volatile("s_waitcnt vmcnt(8)" ::: "memory")
#define WAITV4() asm volatile("s_waitcnt vmcnt(4)" ::: "memory")
#define WAITV0() asm volatile("s_waitcnt vmcnt(0)" ::: "memory")

__device__ inline u16 f2bf(float f) {
    uint32_t u = __float_as_uint(f);
    u += 0x7fff + ((u >> 16) & 1);   // RNE
    return (u16)(u >> 16);
}

__device__ inline void gll16(const void* g, void* l) {
    __builtin_amdgcn_global_load_lds((gvoid_t*)g, (lvoid_t*)l, 16, 0, 0);
}

__device__ inline f32x4 mfma16(bf16x8 a, bf16x8 b, f32x4 c) {
    return __builtin_amdgcn_mfma_f32_16x16x32_bf16(a, b, c, 0, 0, 0);
}

// ---------------- cast fp32 -> bf16 (vectorized) ----------------
__global__ __launch_bounds__(256) void cast_bf16_kernel(
        const float* __restrict__ in, u16* __restrict__ out, int n4) {
    int i = blockIdx.x * 256 + threadIdx.x;
    if (i >= n4) return;
    f32x4v f = ((const f32x4v*)in)[i];
    u16x4 o;
    o[0] = f2bf(f[0]); o[1] = f2bf(f[1]); o[2] = f2bf(f[2]); o[3] = f2bf(f[3]);
    ((u16x4*)out)[i] = o;
}

// ---------------- transpose + cast: W[K][N] fp32 -> WT[N][K] bf16 ----------------
__global__ __launch_bounds__(256) void trans_cast_kernel(
        const float* __restrict__ W, u16* __restrict__ WT, int K, int N) {
    __shared__ float t[32][33];
    int x = threadIdx.x;           // 0..31
    int y = threadIdx.y;           // 0..7
    int n0 = blockIdx.x * 32;
    int k0 = blockIdx.y * 32;
    for (int yy = y; yy < 32; yy += 8)
        t[yy][x] = W[(size_t)(k0 + yy) * N + n0 + x];
    __syncthreads();
    for (int yy = y; yy < 32; yy += 8)
        WT[(size_t)(n0 + yy) * K + k0 + x] = f2bf(t[x][yy]);
}

// ---------------- small GEMM (128x128 tile): C = A @ Bt^T ----------------
// MODE 0: out0 = bf16[M][N], value=(acc+bias)*scale     (Q proj, scale=0.125)
// MODE 2: out0 = fp32 [M][N]                            (O proj -> d_out)
template <int MODE>
__global__ __launch_bounds__(256) void gemm_bt(
        const u16* __restrict__ A, const u16* __restrict__ Bt,
        const float* __restrict__ bias, int M, int N, int K,
        float scale, void* __restrict__ out0, u16* __restrict__ out1) {
    __shared__ u16 lA[2][128 * 32];
    __shared__ u16 lB[2][128 * 32];
    const int tid = threadIdx.x;
    const int lane = tid & 63, wv = tid >> 6;
    const int c16 = lane & 15, g = lane >> 4;
    const int m0 = blockIdx.y * 128, n0 = blockIdx.x * 128;
    const int wm = (wv >> 1) * 64, wn = (wv & 1) * 64;

    const int i0 = tid, i1 = tid + 256;
    const int r0 = i0 >> 2, cc0 = (i0 & 3) ^ ((r0 >> 1) & 3);
    const int r1 = i1 >> 2, cc1 = (i1 & 3) ^ ((r1 >> 1) & 3);
    const int dst0 = (wv * 64) * 8;
    const int dst1 = (256 + wv * 64) * 8;

    auto stage = [&](int buf, int k0) {
        gll16(A + (size_t)(m0 + r0) * K + k0 + cc0 * 8, &lA[buf][dst0]);
        gll16(A + (size_t)(m0 + r1) * K + k0 + cc1 * 8, &lA[buf][dst1]);
        gll16(Bt + (size_t)(n0 + r0) * K + k0 + cc0 * 8, &lB[buf][dst0]);
        gll16(Bt + (size_t)(n0 + r1) * K + k0 + cc1 * 8, &lB[buf][dst1]);
    };

    f32x4 acc[4][4] = {};
    stage(0, 0);
    __syncthreads();
    int buf = 0;
    for (int k0 = 0; k0 < K; k0 += 32) {
        if (k0 + 32 < K) stage(buf ^ 1, k0 + 32);
        bf16x8 af[4], bfr[4];
#pragma unroll
        for (int m = 0; m < 4; m++) {
            int row = wm + m * 16 + c16;
            af[m] = *(const bf16x8*)&lA[buf][row * 32 + (g ^ ((row >> 1) & 3)) * 8];
        }
#pragma unroll
        for (int n = 0; n < 4; n++) {
            int row = wn + n * 16 + c16;
            bfr[n] = *(const bf16x8*)&lB[buf][row * 32 + (g ^ ((row >> 1) & 3)) * 8];
        }
#pragma unroll
        for (int m = 0; m < 4; m++)
#pragma unroll
            for (int n = 0; n < 4; n++)
                acc[m][n] = mfma16(af[m], bfr[n], acc[m][n]);
        __syncthreads();
        buf ^= 1;
    }

#pragma unroll
    for (int n = 0; n < 4; n++) {
        int col = n0 + wn + n * 16 + c16;
        float bv = bias[col];
#pragma unroll
        for (int m = 0; m < 4; m++) {
            int rowb = m0 + wm + m * 16 + g * 4;
#pragma unroll
            for (int j = 0; j < 4; j++) {
                float v = (acc[m][n][j] + bv) * scale;
                int row = rowb + j;
                if (MODE == 0) {
                    ((u16*)out0)[(size_t)row * N + col] = f2bf(v);
                } else {
                    ((float*)out0)[(size_t)row * N + col] = v;
                }
            }
        }
    }
}

// ---------------- big GEMM: 256x256 tile, 8 waves, 4-deep ring, counted vmcnt ----
__global__ __launch_bounds__(512, 2) void gemm_kv_ring(
        const u16* __restrict__ A, const u16* __restrict__ Bt,
        const float* __restrict__ bias, u16* __restrict__ Kp,
        u16* __restrict__ VpT) {
    __shared__ u16 lds[4][2][256 * 32];   // [slot][A=0/B=1][row*32 + swz-chunk*8]
    const int K = 1024, NT = 32;          // K / 32
    const int tid = threadIdx.x;
    const int lane = tid & 63, wv = tid >> 6;
    const int c16 = lane & 15, g = lane >> 4;

    // T1: XCD-aware swizzle (grid 8x32=256, %8==0 -> simple bijective form)
    const int nwg = gridDim.x * gridDim.y;
    const int bid = blockIdx.y * gridDim.x + blockIdx.x;
    const int cpx = nwg >> 3;
    const int sw = (bid & 7) * cpx + (bid >> 3);
    const int bx = sw % gridDim.x, by = sw / gridDim.x;
    const int m0 = by * 256, n0 = bx * 256;

    const int isB = wv >> 2;
    const int rbase = (wv & 3) * 64;
    const u16* src = isB ? Bt : A;
    const int base0 = isB ? n0 : m0;
    size_t off[4];
    const u16* ldst[4];
#pragma unroll
    for (int i = 0; i < 4; i++) {
        int rl = rbase + i * 16 + (lane >> 2);
        int ch = (lane & 3) ^ ((rl >> 1) & 3);
        off[i] = (size_t)(base0 + rl) * K + ch * 8;
        ldst[i] = &lds[0][0][0] + ((size_t)isB * 256 * 32) + (size_t)(rbase + i * 16) * 32;
    }
    const size_t slotStride = 2 * 256 * 32;

    auto stage = [&](int t) {
        const u16* s0 = src + (size_t)t * 32;
        u16* d = (u16*)ldst[0] + (size_t)(t & 3) * slotStride;
        gll16(s0 + off[0], d);
        gll16(s0 + off[1], d + 16 * 32);
        gll16(s0 + off[2], d + 32 * 32);
        gll16(s0 + off[3], d + 48 * 32);
    };

    const int wm = wv >> 2;
    const int wn = wv & 3;
    f32x4 acc[8][4] = {};

    auto compute = [&](int slot) {
        const u16* la = &lds[slot][0][0];
        const u16* lb = &lds[slot][1][0];
        bf16x8 af[8], bfr[4];
#pragma unroll
        for (int m = 0; m < 8; m++) {
            int row = wm * 128 + m * 16 + c16;
            af[m] = *(const bf16x8*)&la[row * 32 + (g ^ ((row >> 1) & 3)) * 8];
        }
#pragma unroll
        for (int n = 0; n < 4; n++) {
            int row = wn * 64 + n * 16 + c16;
            bfr[n] = *(const bf16x8*)&lb[row * 32 + (g ^ ((row >> 1) & 3)) * 8];
        }
#pragma unroll
        for (int m = 0; m < 8; m++)
#pragma unroll
            for (int n = 0; n < 4; n++)
                acc[m][n] = mfma16(af[m], bfr[n], acc[m][n]);
    };

    stage(0); stage(1); stage(2);

    for (int t = 0; t < NT - 2; ++t) {
        WAITV8();
        BAR();
        if (t + 3 < NT) stage(t + 3);
        compute(t & 3);
    }
    WAITV4(); BAR(); compute((NT - 2) & 3);
    WAITV0(); BAR(); compute((NT - 1) & 3);

    const bool isV = (n0 >= 1024);
#pragma unroll
    for (int n = 0; n < 4; n++) {
        int col = n0 + wn * 64 + n * 16 + c16;
        float bv = bias[col];
#pragma unroll
        for (int m = 0; m < 8; m++) {
            int rowb = m0 + wm * 128 + m * 16 + g * 4;
            if (isV) {
                u16x4 pk;
#pragma unroll
                for (int j = 0; j < 4; j++) pk[j] = f2bf(acc[m][n][j] + bv);
                *(u16x4*)&VpT[(size_t)(col - 1024) * 8192 + rowb] = pk;
            } else {
#pragma unroll
                for (int j = 0; j < 4; j++)
                    Kp[(size_t)(rowb + j) * 1024 + col] = f2bf(acc[m][n][j] + bv);
            }
        }
    }
}

// ---------------- flash attention, kv-split x2, 4-deep ring ----------------
// grid: (qblk=8, h=16, b*2+split=8); 4 waves x 16 q-rows; 16 kv tiles of 64
// writes unnormalized partials: Opart[sp][rowhead][64] f32, ml[sp][rowhead][2]
__global__ __launch_bounds__(256) void attn_split_kernel(
        const u16* __restrict__ Qp, const u16* __restrict__ Kp,
        const u16* __restrict__ VpT, float* __restrict__ Opart,
        float* __restrict__ ml) {
    __shared__ u16 lKV[4][2][64 * 64];   // [slot][K=0/V=1]
    __shared__ u16 lP[4][16][72];
    const int NT = 16;
    const int tid = threadIdx.x;
    const int lane = tid & 63, wv = tid >> 6;
    const int c16 = lane & 15, g = lane >> 4;
    const int qblk = blockIdx.x, h = blockIdx.y;
    const int b = blockIdx.z >> 1, sp = blockIdx.z & 1;
    const int kvbase = sp * 1024;

    const int qrow = b * 512 + qblk * 64 + wv * 16 + c16;
    bf16x8 qf[2];
    qf[0] = *(const bf16x8*)(Qp + (size_t)qrow * 1024 + h * 64 + g * 8);
    qf[1] = *(const bf16x8*)(Qp + (size_t)qrow * 1024 + h * 64 + 32 + g * 8);

    f32x4 acc[4] = {};
    float mrow[4] = {-1e30f, -1e30f, -1e30f, -1e30f};
    float lrow[4] = {0.f, 0.f, 0.f, 0.f};

    const int i0 = tid, i1 = tid + 256;
    const int r0 = i0 >> 3, c0 = (i0 & 7) ^ (r0 & 7);
    const int r1 = i1 >> 3, c1 = (i1 & 7) ^ (r1 & 7);
    const int dst0 = (wv * 64) * 8, dst1 = (256 + wv * 64) * 8;

    auto stageKV = [&](int t) {
        int kv0 = kvbase + t * 64;
        u16* dK = &lKV[t & 3][0][0];
        u16* dV = &lKV[t & 3][1][0];
        gll16(Kp + (size_t)(b * 2048 + kv0 + r0) * 1024 + h * 64 + c0 * 8, dK + dst0);
        gll16(Kp + (size_t)(b * 2048 + kv0 + r1) * 1024 + h * 64 + c1 * 8, dK + dst1);
        gll16(VpT + (size_t)(h * 64 + r0) * 8192 + b * 2048 + kv0 + c0 * 8, dV + dst0);
        gll16(VpT + (size_t)(h * 64 + r1) * 8192 + b * 2048 + kv0 + c1 * 8, dV + dst1);
    };

    auto compute = [&](int t) {
        const u16* lK = &lKV[t & 3][0][0];
        const u16* lV = &lKV[t & 3][1][0];

        f32x4 s[4];
#pragma unroll
        for (int n = 0; n < 4; n++) {
            s[n] = f32x4{0.f, 0.f, 0.f, 0.f};
            int key = n * 16 + c16;
#pragma unroll
            for (int kk = 0; kk < 2; kk++) {
                bf16x8 kf = *(const bf16x8*)&lK[key * 64 + (((kk * 4 + g) ^ (key & 7))) * 8];
                s[n] = mfma16(qf[kk], kf, s[n]);
            }
        }

        float p[4][4];
#pragma unroll
        for (int j = 0; j < 4; j++) {
            float v = fmaxf(fmaxf(s[0][j], s[1][j]), fmaxf(s[2][j], s[3][j]));
#pragma unroll
            for (int off = 1; off < 16; off <<= 1) v = fmaxf(v, __shfl_xor(v, off));
            float mn = fmaxf(mrow[j], v);
            float al = __expf(mrow[j] - mn);
            mrow[j] = mn;
            float sum = 0.f;
#pragma unroll
            for (int n = 0; n < 4; n++) { p[n][j] = __expf(s[n][j] - mn); sum += p[n][j]; }
#pragma unroll
            for (int off = 1; off < 16; off <<= 1) sum += __shfl_xor(sum, off);
            lrow[j] = lrow[j] * al + sum;
#pragma unroll
            for (int n = 0; n < 4; n++) acc[n][j] *= al;
        }

#pragma unroll
        for (int j = 0; j < 4; j++)
#pragma unroll
            for (int n = 0; n < 4; n++)
                lP[wv][g * 4 + j][n * 16 + c16] = f2bf(p[n][j]);

#pragma unroll
        for (int kk2 = 0; kk2 < 2; kk2++) {
            union { bf16x8 v8; u16x4 v4[2]; } pu;
            const u16* pp = &lP[wv][c16][kk2 * 32 + g * 8];
            pu.v4[0] = *(const u16x4*)pp;
            pu.v4[1] = *(const u16x4*)(pp + 4);
#pragma unroll
            for (int nd = 0; nd < 4; nd++) {
                int d = nd * 16 + c16;
                bf16x8 vf = *(const bf16x8*)&lV[d * 64 + (((kk2 * 4 + g) ^ (d & 7))) * 8];
                acc[nd] = mfma16(pu.v8, vf, acc[nd]);
            }
        }
    };

    stageKV(0); stageKV(1); stageKV(2);
    for (int t = 0; t < NT - 2; ++t) {
        WAITV8();
        BAR();
        if (t + 3 < NT) stageKV(t + 3);
        compute(t);
    }
    WAITV4(); BAR(); compute(NT - 2);
    WAITV0(); BAR(); compute(NT - 1);

    // write partials (unnormalized O, running m and l)
#pragma unroll
    for (int j = 0; j < 4; j++) {
        int rowq = b * 512 + qblk * 64 + wv * 16 + g * 4 + j;
        size_t idx = (size_t)sp * 32768 + (size_t)rowq * 16 + h;
#pragma unroll
        for (int nd = 0; nd < 4; nd++)
            Opart[idx * 64 + nd * 16 + c16] = acc[nd][j];
        if (c16 == 0) {
            ml[idx * 2] = mrow[j];
            ml[idx * 2 + 1] = lrow[j];
        }
    }
}

// ---------------- combine the 2 kv-split partials -> X bf16 ----------------
__global__ __launch_bounds__(256) void attn_combine_kernel(
        const float* __restrict__ Opart, const float* __restrict__ ml,
        u16* __restrict__ X) {
    const int tid = threadIdx.x;
    const int r = blockIdx.x * 4 + (tid >> 6);   // rowhead 0..32767
    const int d = tid & 63;
    float m0 = ml[(size_t)r * 2], l0 = ml[(size_t)r * 2 + 1];
    float m1 = ml[(size_t)(32768 + r) * 2], l1 = ml[(size_t)(32768 + r) * 2 + 1];
    float M = fmaxf(m0, m1);
    float a0 = __expf(m0 - M), a1 = __expf(m1 - M);
    float li = 1.f / (l0 * a0 + l1 * a1);
    float o0 = Opart[(size_t)r * 64 + d];
    float o1 = Opart[(size_t)(32768 + r) * 64 + d];
    float o = (o0 * a0 + o1 * a1) * li;
    int qrow = r >> 4, h = r & 15;
    X[(size_t)qrow * 1024 + h * 64 + d] = f2bf(o);
}

// ---------------- launch ----------------
extern "C" void kernel_launch(void* const* d_in, const int* in_sizes, int n_in,
                              void* d_out, int out_size, void* d_ws, size_t ws_size,
                              hipStream_t stream) {
    const float* queries = (const float*)d_in[0];   // [4,512,1024]
    const float* context = (const float*)d_in[1];   // [4,2048,1024]
    const float* Wq      = (const float*)d_in[2];   // [1024,1024]
    const float* bq      = (const float*)d_in[3];   // [1024]
    const float* Wkv     = (const float*)d_in[4];   // [1024,2048]
    const float* bkv     = (const float*)d_in[5];   // [2048]
    const float* Wo      = (const float*)d_in[6];   // [1024,1024]
    const float* bo      = (const float*)d_in[7];   // [1024]

    char* ws = (char*)d_ws;
    u16* qb   = (u16*)(ws);                         // queries bf16   4MB (dead after Q-proj)
    u16* cb   = (u16*)(ws + (4ull  << 20));         // context bf16  16MB (dead after KV GEMM)
    u16* WqT  = (u16*)(ws + (20ull << 20));         // Wq^T bf16      2MB
    u16* WkvT = (u16*)(ws + (22ull << 20));         // Wkv^T bf16     4MB
    u16* WoT  = (u16*)(ws + (26ull << 20));         // Wo^T bf16      2MB
    u16* Qp   = (u16*)(ws + (28ull << 20));         // q proj (x1/8)  4MB
    u16* Kp   = (u16*)(ws + (32ull << 20));         // k proj        16MB
    u16* VpT  = (u16*)(ws + (48ull << 20));         // v proj ^T     16MB
    u16* X    = (u16*)(ws + (64ull << 20));         // attn out       4MB
    float* ml    = (float*)qb;                      // 1MB, aliases dead qb
    float* Opart = (float*)cb;                      // 16MB, aliases dead cb

    cast_bf16_kernel<<<dim3(2048), dim3(256), 0, stream>>>(queries, qb, 524288);
    cast_bf16_kernel<<<dim3(8192), dim3(256), 0, stream>>>(context, cb, 2097152);
    trans_cast_kernel<<<dim3(32, 32), dim3(32, 8), 0, stream>>>(Wq, WqT, 1024, 1024);
    trans_cast_kernel<<<dim3(64, 32), dim3(32, 8), 0, stream>>>(Wkv, WkvT, 1024, 2048);
    trans_cast_kernel<<<dim3(32, 32), dim3(32, 8), 0, stream>>>(Wo, WoT, 1024, 1024);

    gemm_bt<0><<<dim3(8, 16), dim3(256), 0, stream>>>(qb, WqT, bq, 2048, 1024, 1024,
                                                      0.125f, (void*)Qp, (u16*)nullptr);
    gemm_kv_ring<<<dim3(8, 32), dim3(512), 0, stream>>>(cb, WkvT, bkv, Kp, VpT);
    attn_split_kernel<<<dim3(8, 16, 8), dim3(256), 0, stream>>>(Qp, Kp, VpT, Opart, ml);
    attn_combine_kernel<<<dim3(8192), dim3(256), 0, stream>>>(Opart, ml, X);
    gemm_bt<2><<<dim3(8, 16), dim3(256), 0, stream>>>(X, WoT, bo, 2048, 1024, 1024,
                                                      1.0f, d_out, (u16*)nullptr);
}

// Round 4
// 174.533 us; speedup vs baseline: 1.0674x; 1.0674x over previous
//
#include <hip/hip_runtime.h>
#include <hip/hip_bf16.h>
#include <stdint.h>

typedef unsigned short u16;
typedef __attribute__((ext_vector_type(8))) __bf16 bf16x8;
typedef __attribute__((ext_vector_type(4))) float f32x4;
typedef __attribute__((ext_vector_type(4))) u16 u16x4;
typedef __attribute__((ext_vector_type(4))) float f32x4v;

typedef __attribute__((address_space(1))) void gvoid_t;
typedef __attribute__((address_space(3))) void lvoid_t;

#define BAR()    asm volatile("s_barrier" ::: "memory")
#define WAITV8() asm volatile("s_waitcnt vmcnt(8)" ::: "memory")
#define WAITV4() asm volatile("s_waitcnt vmcnt(4)" ::: "memory")
#define WAITV0() asm volatile("s_waitcnt vmcnt(0)" ::: "memory")

__device__ inline u16 f2bf(float f) {
    uint32_t u = __float_as_uint(f);
    u += 0x7fff + ((u >> 16) & 1);   // RNE
    return (u16)(u >> 16);
}

__device__ inline void gll16(const void* g, void* l) {
    __builtin_amdgcn_global_load_lds((gvoid_t*)g, (lvoid_t*)l, 16, 0, 0);
}

__device__ inline f32x4 mfma16(bf16x8 a, bf16x8 b, f32x4 c) {
    return __builtin_amdgcn_mfma_f32_16x16x32_bf16(a, b, c, 0, 0, 0);
}

// ---------------- cast fp32 -> bf16 (vectorized) ----------------
__global__ __launch_bounds__(256) void cast_bf16_kernel(
        const float* __restrict__ in, u16* __restrict__ out, int n4) {
    int i = blockIdx.x * 256 + threadIdx.x;
    if (i >= n4) return;
    f32x4v f = ((const f32x4v*)in)[i];
    u16x4 o;
    o[0] = f2bf(f[0]); o[1] = f2bf(f[1]); o[2] = f2bf(f[2]); o[3] = f2bf(f[3]);
    ((u16x4*)out)[i] = o;
}

// ---------------- transpose + cast: W[K][N] fp32 -> WT[N][K] bf16 ----------------
__global__ __launch_bounds__(256) void trans_cast_kernel(
        const float* __restrict__ W, u16* __restrict__ WT, int K, int N) {
    __shared__ float t[32][33];
    int x = threadIdx.x;           // 0..31
    int y = threadIdx.y;           // 0..7
    int n0 = blockIdx.x * 32;
    int k0 = blockIdx.y * 32;
    for (int yy = y; yy < 32; yy += 8)
        t[yy][x] = W[(size_t)(k0 + yy) * N + n0 + x];
    __syncthreads();
    for (int yy = y; yy < 32; yy += 8)
        WT[(size_t)(n0 + yy) * K + k0 + x] = f2bf(t[x][yy]);
}

// ---------------- small GEMM (128x128 tile): C = A @ Bt^T ----------------
// MODE 0: out0 = bf16[M][N], value=(acc+bias)*scale     (Q proj, scale=0.125)
// MODE 2: out0 = fp32 [M][N]                            (O proj -> d_out)
template <int MODE>
__global__ __launch_bounds__(256) void gemm_bt(
        const u16* __restrict__ A, const u16* __restrict__ Bt,
        const float* __restrict__ bias, int M, int N, int K,
        float scale, void* __restrict__ out0, u16* __restrict__ out1) {
    __shared__ u16 lA[2][128 * 32];
    __shared__ u16 lB[2][128 * 32];
    const int tid = threadIdx.x;
    const int lane = tid & 63, wv = tid >> 6;
    const int c16 = lane & 15, g = lane >> 4;
    const int m0 = blockIdx.y * 128, n0 = blockIdx.x * 128;
    const int wm = (wv >> 1) * 64, wn = (wv & 1) * 64;

    const int i0 = tid, i1 = tid + 256;
    const int r0 = i0 >> 2, cc0 = (i0 & 3) ^ ((r0 >> 1) & 3);
    const int r1 = i1 >> 2, cc1 = (i1 & 3) ^ ((r1 >> 1) & 3);
    const int dst0 = (wv * 64) * 8;
    const int dst1 = (256 + wv * 64) * 8;

    auto stage = [&](int buf, int k0) {
        gll16(A + (size_t)(m0 + r0) * K + k0 + cc0 * 8, &lA[buf][dst0]);
        gll16(A + (size_t)(m0 + r1) * K + k0 + cc1 * 8, &lA[buf][dst1]);
        gll16(Bt + (size_t)(n0 + r0) * K + k0 + cc0 * 8, &lB[buf][dst0]);
        gll16(Bt + (size_t)(n0 + r1) * K + k0 + cc1 * 8, &lB[buf][dst1]);
    };

    f32x4 acc[4][4] = {};
    stage(0, 0);
    __syncthreads();
    int buf = 0;
    for (int k0 = 0; k0 < K; k0 += 32) {
        if (k0 + 32 < K) stage(buf ^ 1, k0 + 32);
        bf16x8 af[4], bfr[4];
#pragma unroll
        for (int m = 0; m < 4; m++) {
            int row = wm + m * 16 + c16;
            af[m] = *(const bf16x8*)&lA[buf][row * 32 + (g ^ ((row >> 1) & 3)) * 8];
        }
#pragma unroll
        for (int n = 0; n < 4; n++) {
            int row = wn + n * 16 + c16;
            bfr[n] = *(const bf16x8*)&lB[buf][row * 32 + (g ^ ((row >> 1) & 3)) * 8];
        }
#pragma unroll
        for (int m = 0; m < 4; m++)
#pragma unroll
            for (int n = 0; n < 4; n++)
                acc[m][n] = mfma16(af[m], bfr[n], acc[m][n]);
        __syncthreads();
        buf ^= 1;
    }

#pragma unroll
    for (int n = 0; n < 4; n++) {
        int col = n0 + wn + n * 16 + c16;
        float bv = bias[col];
#pragma unroll
        for (int m = 0; m < 4; m++) {
            int rowb = m0 + wm + m * 16 + g * 4;
#pragma unroll
            for (int j = 0; j < 4; j++) {
                float v = (acc[m][n][j] + bv) * scale;
                int row = rowb + j;
                if (MODE == 0) {
                    ((u16*)out0)[(size_t)row * N + col] = f2bf(v);
                } else {
                    ((float*)out0)[(size_t)row * N + col] = v;
                }
            }
        }
    }
}

// ---------------- big GEMM: 256x256 tile, 8 waves, 4-deep ring, counted vmcnt ----
__global__ __launch_bounds__(512, 2) void gemm_kv_ring(
        const u16* __restrict__ A, const u16* __restrict__ Bt,
        const float* __restrict__ bias, u16* __restrict__ Kp,
        u16* __restrict__ VpT) {
    __shared__ u16 lds[4][2][256 * 32];   // [slot][A=0/B=1][row*32 + swz-chunk*8]
    const int K = 1024, NT = 32;          // K / 32
    const int tid = threadIdx.x;
    const int lane = tid & 63, wv = tid >> 6;
    const int c16 = lane & 15, g = lane >> 4;

    // T1: XCD-aware swizzle (grid 8x32=256, %8==0 -> simple bijective form)
    const int nwg = gridDim.x * gridDim.y;
    const int bid = blockIdx.y * gridDim.x + blockIdx.x;
    const int cpx = nwg >> 3;
    const int sw = (bid & 7) * cpx + (bid >> 3);
    const int bx = sw % gridDim.x, by = sw / gridDim.x;
    const int m0 = by * 256, n0 = bx * 256;

    const int isB = wv >> 2;
    const int rbase = (wv & 3) * 64;
    const u16* src = isB ? Bt : A;
    const int base0 = isB ? n0 : m0;
    size_t off[4];
    const u16* ldst[4];
#pragma unroll
    for (int i = 0; i < 4; i++) {
        int rl = rbase + i * 16 + (lane >> 2);
        int ch = (lane & 3) ^ ((rl >> 1) & 3);
        off[i] = (size_t)(base0 + rl) * K + ch * 8;
        ldst[i] = &lds[0][0][0] + ((size_t)isB * 256 * 32) + (size_t)(rbase + i * 16) * 32;
    }
    const size_t slotStride = 2 * 256 * 32;

    auto stage = [&](int t) {
        const u16* s0 = src + (size_t)t * 32;
        u16* d = (u16*)ldst[0] + (size_t)(t & 3) * slotStride;
        gll16(s0 + off[0], d);
        gll16(s0 + off[1], d + 16 * 32);
        gll16(s0 + off[2], d + 32 * 32);
        gll16(s0 + off[3], d + 48 * 32);
    };

    const int wm = wv >> 2;
    const int wn = wv & 3;
    f32x4 acc[8][4] = {};

    auto compute = [&](int slot) {
        const u16* la = &lds[slot][0][0];
        const u16* lb = &lds[slot][1][0];
        bf16x8 af[8], bfr[4];
#pragma unroll
        for (int m = 0; m < 8; m++) {
            int row = wm * 128 + m * 16 + c16;
            af[m] = *(const bf16x8*)&la[row * 32 + (g ^ ((row >> 1) & 3)) * 8];
        }
#pragma unroll
        for (int n = 0; n < 4; n++) {
            int row = wn * 64 + n * 16 + c16;
            bfr[n] = *(const bf16x8*)&lb[row * 32 + (g ^ ((row >> 1) & 3)) * 8];
        }
#pragma unroll
        for (int m = 0; m < 8; m++)
#pragma unroll
            for (int n = 0; n < 4; n++)
                acc[m][n] = mfma16(af[m], bfr[n], acc[m][n]);
    };

    stage(0); stage(1); stage(2);

    for (int t = 0; t < NT - 2; ++t) {
        WAITV8();
        BAR();
        if (t + 3 < NT) stage(t + 3);
        compute(t & 3);
    }
    WAITV4(); BAR(); compute((NT - 2) & 3);
    WAITV0(); BAR(); compute((NT - 1) & 3);

    const bool isV = (n0 >= 1024);
#pragma unroll
    for (int n = 0; n < 4; n++) {
        int col = n0 + wn * 64 + n * 16 + c16;
        float bv = bias[col];
#pragma unroll
        for (int m = 0; m < 8; m++) {
            int rowb = m0 + wm * 128 + m * 16 + g * 4;
            if (isV) {
                u16x4 pk;
#pragma unroll
                for (int j = 0; j < 4; j++) pk[j] = f2bf(acc[m][n][j] + bv);
                *(u16x4*)&VpT[(size_t)(col - 1024) * 8192 + rowb] = pk;
            } else {
#pragma unroll
                for (int j = 0; j < 4; j++)
                    Kp[(size_t)(rowb + j) * 1024 + col] = f2bf(acc[m][n][j] + bv);
            }
        }
    }
}

// ---------------- flash attention, kv-split x2, swapped-QK softmax ----------------
// grid: (qblk=8, h=16, b*2+split=8); 4 waves x 16 q-rows; 16 kv tiles of 64
// LDS = 2-slot KV dbuf (32KB) + swizzled lP (8KB) = 40960B -> 4 blocks/CU.
// Swapped S^T = mfma(K,Q): lane holds 16 scores for q=c16 -> softmax reduce is
// in-register + 2 shuffles (vs 32 dependent shuffles in the row-spread layout).
__global__ __launch_bounds__(256) void attn_split_kernel(
        const u16* __restrict__ Qp, const u16* __restrict__ Kp,
        const u16* __restrict__ VpT, float* __restrict__ Opart,
        float* __restrict__ ml) {
    __shared__ u16 lKV[2][2][64 * 64];   // [slot][K=0/V=1]
    __shared__ u16 lP[4][16][64];        // [wave][q][key ^ ((q&7)<<3)]
    const int NT = 16;
    const int tid = threadIdx.x;
    const int lane = tid & 63, wv = tid >> 6;
    const int c16 = lane & 15, g = lane >> 4;
    const int qblk = blockIdx.x, h = blockIdx.y;
    const int b = blockIdx.z >> 1, sp = blockIdx.z & 1;
    const int kvbase = sp * 1024;

    const int qrow = b * 512 + qblk * 64 + wv * 16 + c16;
    bf16x8 qf[2];
    qf[0] = *(const bf16x8*)(Qp + (size_t)qrow * 1024 + h * 64 + g * 8);
    qf[1] = *(const bf16x8*)(Qp + (size_t)qrow * 1024 + h * 64 + 32 + g * 8);

    f32x4 acc[4] = {};
    float m_s = -1e30f, l_s = 0.f;       // running max/sum for q-row = c16

    const int i0 = tid, i1 = tid + 256;
    const int r0 = i0 >> 3, c0 = (i0 & 7) ^ (r0 & 7);
    const int r1 = i1 >> 3, c1 = (i1 & 7) ^ (r1 & 7);
    const int dst0 = (wv * 64) * 8, dst1 = (256 + wv * 64) * 8;

    auto stageKV = [&](int buf, int t) {
        int kv0 = kvbase + t * 64;
        u16* dK = &lKV[buf][0][0];
        u16* dV = &lKV[buf][1][0];
        gll16(Kp + (size_t)(b * 2048 + kv0 + r0) * 1024 + h * 64 + c0 * 8, dK + dst0);
        gll16(Kp + (size_t)(b * 2048 + kv0 + r1) * 1024 + h * 64 + c1 * 8, dK + dst1);
        gll16(VpT + (size_t)(h * 64 + r0) * 8192 + b * 2048 + kv0 + c0 * 8, dV + dst0);
        gll16(VpT + (size_t)(h * 64 + r1) * 8192 + b * 2048 + kv0 + c1 * 8, dV + dst1);
    };

    const int pswz = (c16 & 7) << 3;     // lP column XOR (keeps 8-key blocks contiguous)

    stageKV(0, 0);
    int buf = 0;
    for (int t = 0; t < NT; ++t) {
        __syncthreads();                  // tile t landed; buf^1 free to overwrite
        if (t + 1 < NT) stageKV(buf ^ 1, t + 1);

        const u16* lK = &lKV[buf][0][0];
        const u16* lV = &lKV[buf][1][0];

        // S^T = K Q^T : s[n] holds keys (n*16 + g*4 + j) for q = c16
        f32x4 s[4];
#pragma unroll
        for (int n = 0; n < 4; n++) {
            s[n] = f32x4{0.f, 0.f, 0.f, 0.f};
            int key = n * 16 + c16;
#pragma unroll
            for (int kk = 0; kk < 2; kk++) {
                bf16x8 kf = *(const bf16x8*)&lK[key * 64 + (((kk * 4 + g) ^ (key & 7))) * 8];
                s[n] = mfma16(kf, qf[kk], s[n]);
            }
        }

        // online softmax, q = c16: in-register reduce + 2 shuffles
        float mx = s[0][0];
#pragma unroll
        for (int n = 0; n < 4; n++)
#pragma unroll
            for (int j = 0; j < 4; j++) mx = fmaxf(mx, s[n][j]);
        mx = fmaxf(mx, __shfl_xor(mx, 16));
        mx = fmaxf(mx, __shfl_xor(mx, 32));
        float mn = fmaxf(m_s, mx);
        float al = __expf(m_s - mn);
        m_s = mn;
        float p[4][4], sum = 0.f;
#pragma unroll
        for (int n = 0; n < 4; n++)
#pragma unroll
            for (int j = 0; j < 4; j++) { p[n][j] = __expf(s[n][j] - mn); sum += p[n][j]; }
        sum += __shfl_xor(sum, 16);
        sum += __shfl_xor(sum, 32);
        l_s = l_s * al + sum;

        // redistribute al to the O-row-holding lanes (rows g*4+j), independent shuffles
        float alr[4];
#pragma unroll
        for (int j = 0; j < 4; j++) alr[j] = __shfl(al, g * 4 + j);
#pragma unroll
        for (int nd = 0; nd < 4; nd++)
#pragma unroll
            for (int j = 0; j < 4; j++) acc[nd][j] *= alr[j];

        // P^T -> lP in [q][key] layout (XOR-swizzled, 2-way banks = free)
#pragma unroll
        for (int n = 0; n < 4; n++)
#pragma unroll
            for (int j = 0; j < 4; j++)
                lP[wv][c16][(n * 16 + g * 4 + j) ^ pswz] = f2bf(p[n][j]);

        // O += P @ V (A-fragment: 8 contiguous keys at kk2*32 + g*8, 16B aligned)
#pragma unroll
        for (int kk2 = 0; kk2 < 2; kk2++) {
            bf16x8 pa = *(const bf16x8*)&lP[wv][c16][(kk2 * 32 + g * 8) ^ pswz];
#pragma unroll
            for (int nd = 0; nd < 4; nd++) {
                int d = nd * 16 + c16;
                bf16x8 vf = *(const bf16x8*)&lV[d * 64 + (((kk2 * 4 + g) ^ (d & 7))) * 8];
                acc[nd] = mfma16(pa, vf, acc[nd]);
            }
        }
        buf ^= 1;
    }

    // write partials: unnormalized O (rows g*4+j) + per-row m,l (lanes g==0, row c16)
#pragma unroll
    for (int j = 0; j < 4; j++) {
        int rowq = b * 512 + qblk * 64 + wv * 16 + g * 4 + j;
        size_t idx = (size_t)sp * 32768 + (size_t)rowq * 16 + h;
#pragma unroll
        for (int nd = 0; nd < 4; nd++)
            Opart[idx * 64 + nd * 16 + c16] = acc[nd][j];
    }
    if (g == 0) {
        int rowq = b * 512 + qblk * 64 + wv * 16 + c16;
        size_t idx = (size_t)sp * 32768 + (size_t)rowq * 16 + h;
        ml[idx * 2] = m_s;
        ml[idx * 2 + 1] = l_s;
    }
}

// ---------------- combine the 2 kv-split partials -> X bf16 ----------------
__global__ __launch_bounds__(256) void attn_combine_kernel(
        const float* __restrict__ Opart, const float* __restrict__ ml,
        u16* __restrict__ X) {
    const int tid = threadIdx.x;
    const int r = blockIdx.x * 4 + (tid >> 6);   // rowhead 0..32767
    const int d = tid & 63;
    float m0 = ml[(size_t)r * 2], l0 = ml[(size_t)r * 2 + 1];
    float m1 = ml[(size_t)(32768 + r) * 2], l1 = ml[(size_t)(32768 + r) * 2 + 1];
    float M = fmaxf(m0, m1);
    float a0 = __expf(m0 - M), a1 = __expf(m1 - M);
    float li = 1.f / (l0 * a0 + l1 * a1);
    float o0 = Opart[(size_t)r * 64 + d];
    float o1 = Opart[(size_t)(32768 + r) * 64 + d];
    float o = (o0 * a0 + o1 * a1) * li;
    int qrow = r >> 4, h = r & 15;
    X[(size_t)qrow * 1024 + h * 64 + d] = f2bf(o);
}

// ---------------- launch ----------------
extern "C" void kernel_launch(void* const* d_in, const int* in_sizes, int n_in,
                              void* d_out, int out_size, void* d_ws, size_t ws_size,
                              hipStream_t stream) {
    const float* queries = (const float*)d_in[0];   // [4,512,1024]
    const float* context = (const float*)d_in[1];   // [4,2048,1024]
    const float* Wq      = (const float*)d_in[2];   // [1024,1024]
    const float* bq      = (const float*)d_in[3];   // [1024]
    const float* Wkv     = (const float*)d_in[4];   // [1024,2048]
    const float* bkv     = (const float*)d_in[5];   // [2048]
    const float* Wo      = (const float*)d_in[6];   // [1024,1024]
    const float* bo      = (const float*)d_in[7];   // [1024]

    char* ws = (char*)d_ws;
    u16* qb   = (u16*)(ws);                         // queries bf16   4MB (dead after Q-proj)
    u16* cb   = (u16*)(ws + (4ull  << 20));         // context bf16  16MB (dead after KV GEMM)
    u16* WqT  = (u16*)(ws + (20ull << 20));         // Wq^T bf16      2MB
    u16* WkvT = (u16*)(ws + (22ull << 20));         // Wkv^T bf16     4MB
    u16* WoT  = (u16*)(ws + (26ull << 20));         // Wo^T bf16      2MB
    u16* Qp   = (u16*)(ws + (28ull << 20));         // q proj (x1/8)  4MB
    u16* Kp   = (u16*)(ws + (32ull << 20));         // k proj        16MB
    u16* VpT  = (u16*)(ws + (48ull << 20));         // v proj ^T     16MB
    u16* X    = (u16*)(ws + (64ull << 20));         // attn out       4MB
    float* ml    = (float*)qb;                      // 1MB, aliases dead qb
    float* Opart = (float*)cb;                      // 16MB, aliases dead cb

    cast_bf16_kernel<<<dim3(2048), dim3(256), 0, stream>>>(queries, qb, 524288);
    cast_bf16_kernel<<<dim3(8192), dim3(256), 0, stream>>>(context, cb, 2097152);
    trans_cast_kernel<<<dim3(32, 32), dim3(32, 8), 0, stream>>>(Wq, WqT, 1024, 1024);
    trans_cast_kernel<<<dim3(64, 32), dim3(32, 8), 0, stream>>>(Wkv, WkvT, 1024, 2048);
    trans_cast_kernel<<<dim3(32, 32), dim3(32, 8), 0, stream>>>(Wo, WoT, 1024, 1024);

    gemm_bt<0><<<dim3(8, 16), dim3(256), 0, stream>>>(qb, WqT, bq, 2048, 1024, 1024,
                                                      0.125f, (void*)Qp, (u16*)nullptr);
    gemm_kv_ring<<<dim3(8, 32), dim3(512), 0, stream>>>(cb, WkvT, bkv, Kp, VpT);
    attn_split_kernel<<<dim3(8, 16, 8), dim3(256), 0, stream>>>(Qp, Kp, VpT, Opart, ml);
    attn_combine_kernel<<<dim3(8192), dim3(256), 0, stream>>>(Opart, ml, X);
    gemm_bt<2><<<dim3(8, 16), dim3(256), 0, stream>>>(X, WoT, bo, 2048, 1024, 1024,
                                                      1.0f, d_out, (u16*)nullptr);
}

// Round 6
// 153.506 us; speedup vs baseline: 1.2136x; 1.1370x over previous
//
#include <hip/hip_runtime.h>
#include <hip/hip_bf16.h>
#include <stdint.h>

typedef unsigned short u16;
typedef __attribute__((ext_vector_type(8))) __bf16 bf16x8;
typedef __attribute__((ext_vector_type(2))) __bf16 bf16x2;
typedef __attribute__((ext_vector_type(4))) float f32x4;
typedef __attribute__((ext_vector_type(4))) u16 u16x4;
typedef __attribute__((ext_vector_type(4))) float f32x4v;

typedef __attribute__((address_space(1))) void gvoid_t;
typedef __attribute__((address_space(3))) void lvoid_t;

#define BAR()    asm volatile("s_barrier" ::: "memory")
#define WAITV8() asm volatile("s_waitcnt vmcnt(8)" ::: "memory")
#define WAITV4() asm volatile("s_waitcnt vmcnt(4)" ::: "memory")
#define WAITV0() asm volatile("s_waitcnt vmcnt(0)" ::: "memory")

__device__ inline u16 f2bf(float f) {
    uint32_t u = __float_as_uint(f);
    u += 0x7fff + ((u >> 16) & 1);   // RNE
    return (u16)(u >> 16);
}

__device__ inline void gll16(const void* g, void* l) {
    __builtin_amdgcn_global_load_lds((gvoid_t*)g, (lvoid_t*)l, 16, 0, 0);
}

__device__ inline f32x4 mfma16(bf16x8 a, bf16x8 b, f32x4 c) {
    return __builtin_amdgcn_mfma_f32_16x16x32_bf16(a, b, c, 0, 0, 0);
}

// V slot permutation: context row r (mod 64) -> storage slot, so that the PV
// A-fragment is IN-LANE after swapped QK^T (keys n*16+g*4+j live in lane g).
// slot(r) = (n>>1)*32 + g*8 + (n&1)*4 + j   with n=r>>4, g=(r>>2)&3, j=r&3.
__device__ inline int vslot(int r) {
    int n = r >> 4;
    return ((n >> 1) << 5) + (((r >> 2) & 3) << 3) + ((n & 1) << 2) + (r & 3);
}

// ---------------- cast fp32 -> bf16 (vectorized) ----------------
__global__ __launch_bounds__(256) void cast_bf16_kernel(
        const float* __restrict__ in, u16* __restrict__ out, int n4) {
    int i = blockIdx.x * 256 + threadIdx.x;
    if (i >= n4) return;
    f32x4v f = ((const f32x4v*)in)[i];
    u16x4 o;
    o[0] = f2bf(f[0]); o[1] = f2bf(f[1]); o[2] = f2bf(f[2]); o[3] = f2bf(f[3]);
    ((u16x4*)out)[i] = o;
}

// ---------------- transpose + cast: W[K][N] fp32 -> WT[N][K] bf16 ----------------
__global__ __launch_bounds__(256) void trans_cast_kernel(
        const float* __restrict__ W, u16* __restrict__ WT, int K, int N) {
    __shared__ float t[32][33];
    int x = threadIdx.x;           // 0..31
    int y = threadIdx.y;           // 0..7
    int n0 = blockIdx.x * 32;
    int k0 = blockIdx.y * 32;
    for (int yy = y; yy < 32; yy += 8)
        t[yy][x] = W[(size_t)(k0 + yy) * N + n0 + x];
    __syncthreads();
    for (int yy = y; yy < 32; yy += 8)
        WT[(size_t)(n0 + yy) * K + k0 + x] = f2bf(t[x][yy]);
}

// ---------------- small GEMM (128x128 tile): C = A @ Bt^T ----------------
// MODE 0: out0 = bf16[M][N], value=(acc+bias)*scale     (Q proj)
// MODE 2: out0 = fp32 [M][N]                            (O proj -> d_out)
template <int MODE>
__global__ __launch_bounds__(256) void gemm_bt(
        const u16* __restrict__ A, const u16* __restrict__ Bt,
        const float* __restrict__ bias, int M, int N, int K,
        float scale, void* __restrict__ out0, u16* __restrict__ out1) {
    __shared__ u16 lA[2][128 * 32];
    __shared__ u16 lB[2][128 * 32];
    const int tid = threadIdx.x;
    const int lane = tid & 63, wv = tid >> 6;
    const int c16 = lane & 15, g = lane >> 4;
    const int m0 = blockIdx.y * 128, n0 = blockIdx.x * 128;
    const int wm = (wv >> 1) * 64, wn = (wv & 1) * 64;

    const int i0 = tid, i1 = tid + 256;
    const int r0 = i0 >> 2, cc0 = (i0 & 3) ^ ((r0 >> 1) & 3);
    const int r1 = i1 >> 2, cc1 = (i1 & 3) ^ ((r1 >> 1) & 3);
    const int dst0 = (wv * 64) * 8;
    const int dst1 = (256 + wv * 64) * 8;

    auto stage = [&](int buf, int k0) {
        gll16(A + (size_t)(m0 + r0) * K + k0 + cc0 * 8, &lA[buf][dst0]);
        gll16(A + (size_t)(m0 + r1) * K + k0 + cc1 * 8, &lA[buf][dst1]);
        gll16(Bt + (size_t)(n0 + r0) * K + k0 + cc0 * 8, &lB[buf][dst0]);
        gll16(Bt + (size_t)(n0 + r1) * K + k0 + cc1 * 8, &lB[buf][dst1]);
    };

    f32x4 acc[4][4] = {};
    stage(0, 0);
    __syncthreads();
    int buf = 0;
    for (int k0 = 0; k0 < K; k0 += 32) {
        if (k0 + 32 < K) stage(buf ^ 1, k0 + 32);
        bf16x8 af[4], bfr[4];
#pragma unroll
        for (int m = 0; m < 4; m++) {
            int row = wm + m * 16 + c16;
            af[m] = *(const bf16x8*)&lA[buf][row * 32 + (g ^ ((row >> 1) & 3)) * 8];
        }
#pragma unroll
        for (int n = 0; n < 4; n++) {
            int row = wn + n * 16 + c16;
            bfr[n] = *(const bf16x8*)&lB[buf][row * 32 + (g ^ ((row >> 1) & 3)) * 8];
        }
#pragma unroll
        for (int m = 0; m < 4; m++)
#pragma unroll
            for (int n = 0; n < 4; n++)
                acc[m][n] = mfma16(af[m], bfr[n], acc[m][n]);
        __syncthreads();
        buf ^= 1;
    }

#pragma unroll
    for (int n = 0; n < 4; n++) {
        int col = n0 + wn + n * 16 + c16;
        float bv = bias[col];
#pragma unroll
        for (int m = 0; m < 4; m++) {
            int rowb = m0 + wm + m * 16 + g * 4;
#pragma unroll
            for (int j = 0; j < 4; j++) {
                float v = (acc[m][n][j] + bv) * scale;
                int row = rowb + j;
                if (MODE == 0) {
                    ((u16*)out0)[(size_t)row * N + col] = f2bf(v);
                } else {
                    ((float*)out0)[(size_t)row * N + col] = v;
                }
            }
        }
    }
}

// ---------------- big GEMM: 256x256 tile, 8 waves, 4-deep ring, counted vmcnt ----
// V output stored column-permuted per 64-block (vslot) for in-lane attn PV.
__global__ __launch_bounds__(512, 2) void gemm_kv_ring(
        const u16* __restrict__ A, const u16* __restrict__ Bt,
        const float* __restrict__ bias, u16* __restrict__ Kp,
        u16* __restrict__ VpT) {
    __shared__ u16 lds[4][2][256 * 32];   // [slot][A=0/B=1][row*32 + swz-chunk*8]
    const int K = 1024, NT = 32;          // K / 32
    const int tid = threadIdx.x;
    const int lane = tid & 63, wv = tid >> 6;
    const int c16 = lane & 15, g = lane >> 4;

    // T1: XCD-aware swizzle (grid 8x32=256, %8==0 -> simple bijective form)
    const int nwg = gridDim.x * gridDim.y;
    const int bid = blockIdx.y * gridDim.x + blockIdx.x;
    const int cpx = nwg >> 3;
    const int sw = (bid & 7) * cpx + (bid >> 3);
    const int bx = sw % gridDim.x, by = sw / gridDim.x;
    const int m0 = by * 256, n0 = bx * 256;

    const int isB = wv >> 2;
    const int rbase = (wv & 3) * 64;
    const u16* src = isB ? Bt : A;
    const int base0 = isB ? n0 : m0;
    size_t off[4];
    const u16* ldst[4];
#pragma unroll
    for (int i = 0; i < 4; i++) {
        int rl = rbase + i * 16 + (lane >> 2);
        int ch = (lane & 3) ^ ((rl >> 1) & 3);
        off[i] = (size_t)(base0 + rl) * K + ch * 8;
        ldst[i] = &lds[0][0][0] + ((size_t)isB * 256 * 32) + (size_t)(rbase + i * 16) * 32;
    }
    const size_t slotStride = 2 * 256 * 32;

    auto stage = [&](int t) {
        const u16* s0 = src + (size_t)t * 32;
        u16* d = (u16*)ldst[0] + (size_t)(t & 3) * slotStride;
        gll16(s0 + off[0], d);
        gll16(s0 + off[1], d + 16 * 32);
        gll16(s0 + off[2], d + 32 * 32);
        gll16(s0 + off[3], d + 48 * 32);
    };

    const int wm = wv >> 2;
    const int wn = wv & 3;
    f32x4 acc[8][4] = {};

    auto compute = [&](int slot) {
        const u16* la = &lds[slot][0][0];
        const u16* lb = &lds[slot][1][0];
        bf16x8 af[8], bfr[4];
#pragma unroll
        for (int m = 0; m < 8; m++) {
            int row = wm * 128 + m * 16 + c16;
            af[m] = *(const bf16x8*)&la[row * 32 + (g ^ ((row >> 1) & 3)) * 8];
        }
#pragma unroll
        for (int n = 0; n < 4; n++) {
            int row = wn * 64 + n * 16 + c16;
            bfr[n] = *(const bf16x8*)&lb[row * 32 + (g ^ ((row >> 1) & 3)) * 8];
        }
#pragma unroll
        for (int m = 0; m < 8; m++)
#pragma unroll
            for (int n = 0; n < 4; n++)
                acc[m][n] = mfma16(af[m], bfr[n], acc[m][n]);
    };

    stage(0); stage(1); stage(2);

    for (int t = 0; t < NT - 2; ++t) {
        WAITV8();
        BAR();
        if (t + 3 < NT) stage(t + 3);
        compute(t & 3);
    }
    WAITV4(); BAR(); compute((NT - 2) & 3);
    WAITV0(); BAR(); compute((NT - 1) & 3);

    const bool isV = (n0 >= 1024);
#pragma unroll
    for (int n = 0; n < 4; n++) {
        int col = n0 + wn * 64 + n * 16 + c16;
        float bv = bias[col];
#pragma unroll
        for (int m = 0; m < 8; m++) {
            int rowb = m0 + wm * 128 + m * 16 + g * 4;
            if (isV) {
                u16x4 pk;
#pragma unroll
                for (int j = 0; j < 4; j++) pk[j] = f2bf(acc[m][n][j] + bv);
                // column-permuted store: rows rowb..rowb+3 -> slots vslot(rowb&63)+0..3
                int vcol = (rowb & ~63) + vslot(rowb & 63);
                *(u16x4*)&VpT[(size_t)(col - 1024) * 8192 + vcol] = pk;
            } else {
#pragma unroll
                for (int j = 0; j < 4; j++)
                    Kp[(size_t)(rowb + j) * 1024 + col] = f2bf(acc[m][n][j] + bv);
            }
        }
    }
}

// ---------------- flash attention, kv-split x2, in-lane-P softmax ----------------
// 1-D grid 1024: qblk in HIGH bits so the 8 KV-sharing blocks land on one XCD.
// Per wave: 16 q-rows (q=c16), 16 kv tiles of 64. exp2-domain softmax (Q pre-scaled
// by 0.125*log2e), defer-max (THR=8). P stays IN-LANE: lane (c16,g) holds keys
// n*16+g*4+j for q=c16, which are exactly its PV A-fragment since VpT columns are
// stored in vslot order. No lP LDS, no shuffles. LDS=32KB -> 5 blocks/CU.
__global__ __launch_bounds__(256, 5) void attn_split_kernel(
        const u16* __restrict__ Qp, const u16* __restrict__ Kp,
        const u16* __restrict__ VpT, float* __restrict__ Opart,
        float* __restrict__ ml) {
    __shared__ u16 lKV[2][2][64 * 64];   // [slot][K=0/V=1]  = 32768 B
    const int NT = 16;
    const int tid = threadIdx.x;
    const int lane = tid & 63, wv = tid >> 6;
    const int c16 = lane & 15, g = lane >> 4;
    const int bid = blockIdx.x;
    const int qblk = bid >> 7;            // high bits -> same XCD for all qblk
    const int low = bid & 127;
    const int h = low & 15, z = low >> 4;
    const int b = z >> 1, sp = z & 1;
    const int kvbase = sp * 1024;

    const int qrow = b * 512 + qblk * 64 + wv * 16 + c16;
    bf16x8 qf[2];
    qf[0] = *(const bf16x8*)(Qp + (size_t)qrow * 1024 + h * 64 + g * 8);
    qf[1] = *(const bf16x8*)(Qp + (size_t)qrow * 1024 + h * 64 + 32 + g * 8);

    f32x4 acc[4] = {};
    float m_s = -1e30f, l_s = 0.f;       // q = c16, log2 domain

    const int i0 = tid, i1 = tid + 256;
    const int r0 = i0 >> 3, c0 = (i0 & 7) ^ (r0 & 7);
    const int r1 = i1 >> 3, c1 = (i1 & 7) ^ (r1 & 7);
    const int dst0 = (wv * 64) * 8, dst1 = (256 + wv * 64) * 8;

    auto stageKV = [&](int buf, int t) {
        int kv0 = kvbase + t * 64;
        u16* dK = &lKV[buf][0][0];
        u16* dV = &lKV[buf][1][0];
        gll16(Kp + (size_t)(b * 2048 + kv0 + r0) * 1024 + h * 64 + c0 * 8, dK + dst0);
        gll16(Kp + (size_t)(b * 2048 + kv0 + r1) * 1024 + h * 64 + c1 * 8, dK + dst1);
        gll16(VpT + (size_t)(h * 64 + r0) * 8192 + b * 2048 + kv0 + c0 * 8, dV + dst0);
        gll16(VpT + (size_t)(h * 64 + r1) * 8192 + b * 2048 + kv0 + c1 * 8, dV + dst1);
    };

    stageKV(0, 0);
    int buf = 0;
    for (int t = 0; t < NT; ++t) {
        __syncthreads();                  // tile t landed; buf^1 free
        if (t + 1 < NT) stageKV(buf ^ 1, t + 1);

        const u16* lK = &lKV[buf][0][0];
        const u16* lV = &lKV[buf][1][0];

        // S^T = K Q^T : s[n][j] = S2[q=c16][key = n*16 + g*4 + j]
        f32x4 s[4];
#pragma unroll
        for (int n = 0; n < 4; n++) {
            s[n] = f32x4{0.f, 0.f, 0.f, 0.f};
            int key = n * 16 + c16;
#pragma unroll
            for (int kk = 0; kk < 2; kk++) {
                bf16x8 kf = *(const bf16x8*)&lK[key * 64 + (((kk * 4 + g) ^ (key & 7))) * 8];
                s[n] = mfma16(kf, qf[kk], s[n]);
            }
        }

        // tree max for q=c16 (+2 shuffles across g groups)
        float mn0 = fmaxf(fmaxf(s[0][0], s[0][1]), fmaxf(s[0][2], s[0][3]));
        float mn1 = fmaxf(fmaxf(s[1][0], s[1][1]), fmaxf(s[1][2], s[1][3]));
        float mn2 = fmaxf(fmaxf(s[2][0], s[2][1]), fmaxf(s[2][2], s[2][3]));
        float mn3 = fmaxf(fmaxf(s[3][0], s[3][1]), fmaxf(s[3][2], s[3][3]));
        float mx = fmaxf(fmaxf(mn0, mn1), fmaxf(mn2, mn3));
        mx = fmaxf(mx, __shfl_xor(mx, 16));
        mx = fmaxf(mx, __shfl_xor(mx, 32));

        // defer-max: rescale only when some row grew by > 8 (log2 domain)
        if (!__all(mx - m_s <= 8.0f)) {
            float mn = fmaxf(m_s, mx);
            float al = exp2f(m_s - mn);
            m_s = mn;
            l_s *= al;
            float alr[4];
#pragma unroll
            for (int j = 0; j < 4; j++) alr[j] = __shfl(al, g * 4 + j);
#pragma unroll
            for (int nd = 0; nd < 4; nd++)
#pragma unroll
                for (int j = 0; j < 4; j++) acc[nd][j] *= alr[j];
        }

        // P = exp2(S2 - m), packed to bf16 pairs in-register
        uint32_t r[4][2];
        float sums[4];
#pragma unroll
        for (int n = 0; n < 4; n++) {
            float p0 = exp2f(s[n][0] - m_s);
            float p1 = exp2f(s[n][1] - m_s);
            float p2 = exp2f(s[n][2] - m_s);
            float p3 = exp2f(s[n][3] - m_s);
            sums[n] = (p0 + p1) + (p2 + p3);
            union { bf16x2 h; uint32_t u; } ca, cb;
            ca.h[0] = (__bf16)p0; ca.h[1] = (__bf16)p1;
            cb.h[0] = (__bf16)p2; cb.h[1] = (__bf16)p3;
            r[n][0] = ca.u; r[n][1] = cb.u;
        }
        float sum = (sums[0] + sums[1]) + (sums[2] + sums[3]);
        sum += __shfl_xor(sum, 16);
        sum += __shfl_xor(sum, 32);
        l_s += sum;

        // O += P @ V : A-fragment fully IN-LANE (k-slot (g,kk2,t) holds key
        // (2kk2+(t>>2))*16 + g*4 + (t&3); VpT columns stored in matching order)
#pragma unroll
        for (int kk2 = 0; kk2 < 2; kk2++) {
            union { bf16x8 v8; uint32_t u[4]; } pa;
            pa.u[0] = r[kk2 * 2][0];
            pa.u[1] = r[kk2 * 2][1];
            pa.u[2] = r[kk2 * 2 + 1][0];
            pa.u[3] = r[kk2 * 2 + 1][1];
#pragma unroll
            for (int nd = 0; nd < 4; nd++) {
                int d = nd * 16 + c16;
                bf16x8 vf = *(const bf16x8*)&lV[d * 64 + (((kk2 * 4 + g) ^ (d & 7))) * 8];
                acc[nd] = mfma16(pa.v8, vf, acc[nd]);
            }
        }
        buf ^= 1;
    }

    // write partials: unnormalized O (rows g*4+j) + per-row m,l (g==0 lanes, row c16)
#pragma unroll
    for (int j = 0; j < 4; j++) {
        int rowq = b * 512 + qblk * 64 + wv * 16 + g * 4 + j;
        size_t idx = (size_t)sp * 32768 + (size_t)rowq * 16 + h;
#pragma unroll
        for (int nd = 0; nd < 4; nd++)
            Opart[idx * 64 + nd * 16 + c16] = acc[nd][j];
    }
    if (g == 0) {
        int rowq = b * 512 + qblk * 64 + wv * 16 + c16;
        size_t idx = (size_t)sp * 32768 + (size_t)rowq * 16 + h;
        ml[idx * 2] = m_s;
        ml[idx * 2 + 1] = l_s;
    }
}

// ---------------- combine the 2 kv-split partials -> X bf16 (log2-domain m) ------
__global__ __launch_bounds__(256) void attn_combine_kernel(
        const float* __restrict__ Opart, const float* __restrict__ ml,
        u16* __restrict__ X) {
    const int tid = threadIdx.x;
    const int r = blockIdx.x * 4 + (tid >> 6);   // rowhead 0..32767
    const int d = tid & 63;
    float m0 = ml[(size_t)r * 2], l0 = ml[(size_t)r * 2 + 1];
    float m1 = ml[(size_t)(32768 + r) * 2], l1 = ml[(size_t)(32768 + r) * 2 + 1];
    float M = fmaxf(m0, m1);
    float a0 = exp2f(m0 - M), a1 = exp2f(m1 - M);
    float li = 1.f / (l0 * a0 + l1 * a1);
    float o0 = Opart[(size_t)r * 64 + d];
    float o1 = Opart[(size_t)(32768 + r) * 64 + d];
    float o = (o0 * a0 + o1 * a1) * li;
    int qrow = r >> 4, h = r & 15;
    X[(size_t)qrow * 1024 + h * 64 + d] = f2bf(o);
}

// ---------------- launch ----------------
extern "C" void kernel_launch(void* const* d_in, const int* in_sizes, int n_in,
                              void* d_out, int out_size, void* d_ws, size_t ws_size,
                              hipStream_t stream) {
    const float* queries = (const float*)d_in[0];   // [4,512,1024]
    const float* context = (const float*)d_in[1];   // [4,2048,1024]
    const float* Wq      = (const float*)d_in[2];   // [1024,1024]
    const float* bq      = (const float*)d_in[3];   // [1024]
    const float* Wkv     = (const float*)d_in[4];   // [1024,2048]
    const float* bkv     = (const float*)d_in[5];   // [2048]
    const float* Wo      = (const float*)d_in[6];   // [1024,1024]
    const float* bo      = (const float*)d_in[7];   // [1024]

    char* ws = (char*)d_ws;
    u16* qb   = (u16*)(ws);                         // queries bf16   4MB (dead after Q-proj)
    u16* cb   = (u16*)(ws + (4ull  << 20));         // context bf16  16MB (dead after KV GEMM)
    u16* WqT  = (u16*)(ws + (20ull << 20));         // Wq^T bf16      2MB
    u16* WkvT = (u16*)(ws + (22ull << 20));         // Wkv^T bf16     4MB
    u16* WoT  = (u16*)(ws + (26ull << 20));         // Wo^T bf16      2MB
    u16* Qp   = (u16*)(ws + (28ull << 20));         // q proj (x0.125*log2e) 4MB
    u16* Kp   = (u16*)(ws + (32ull << 20));         // k proj        16MB
    u16* VpT  = (u16*)(ws + (48ull << 20));         // v proj ^T (vslot cols) 16MB
    u16* X    = (u16*)(ws + (64ull << 20));         // attn out       4MB
    float* ml    = (float*)qb;                      // 1MB, aliases dead qb
    float* Opart = (float*)cb;                      // 16MB, aliases dead cb

    cast_bf16_kernel<<<dim3(2048), dim3(256), 0, stream>>>(queries, qb, 524288);
    cast_bf16_kernel<<<dim3(8192), dim3(256), 0, stream>>>(context, cb, 2097152);
    trans_cast_kernel<<<dim3(32, 32), dim3(32, 8), 0, stream>>>(Wq, WqT, 1024, 1024);
    trans_cast_kernel<<<dim3(64, 32), dim3(32, 8), 0, stream>>>(Wkv, WkvT, 1024, 2048);
    trans_cast_kernel<<<dim3(32, 32), dim3(32, 8), 0, stream>>>(Wo, WoT, 1024, 1024);

    // scale = 1/8 * log2(e): scores computed directly in exp2 domain
    gemm_bt<0><<<dim3(8, 16), dim3(256), 0, stream>>>(qb, WqT, bq, 2048, 1024, 1024,
                                                      0.18033688f, (void*)Qp, (u16*)nullptr);
    gemm_kv_ring<<<dim3(8, 32), dim3(512), 0, stream>>>(cb, WkvT, bkv, Kp, VpT);
    attn_split_kernel<<<dim3(1024), dim3(256), 0, stream>>>(Qp, Kp, VpT, Opart, ml);
    attn_combine_kernel<<<dim3(8192), dim3(256), 0, stream>>>(Opart, ml, X);
    gemm_bt<2><<<dim3(8, 16), dim3(256), 0, stream>>>(X, WoT, bo, 2048, 1024, 1024,
                                                      1.0f, d_out, (u16*)nullptr);
}